// Round 1
// baseline (1077.360 us; speedup 1.0000x reference)
//
#include <hip/hip_runtime.h>
#include <hip/hip_fp16.h>

#define NFEAT_IN 21
#define NHID 16
#define NOUT 6
#define BSHIFT 7
#define BW (1 << BSHIFT)     // 128 nodes per bucket
#define NBMAX 2048           // supports n <= 262144
#define EPT 32
#define PB 256
#define CHUNK (PB * EPT)     // 8192 edges per partition block
#define DEPTH 8

typedef unsigned int u32x4 __attribute__((ext_vector_type(4)));

__global__ void k_zero(int* __restrict__ p, int n) {
    int i = blockIdx.x * blockDim.x + threadIdx.x;
    if (i < n) p[i] = 0;
}

__global__ void k_hist(const int* __restrict__ dst, int* __restrict__ bcnt, int ne) {
    __shared__ int lcnt[NBMAX];
    for (int t = threadIdx.x; t < NBMAX; t += blockDim.x) lcnt[t] = 0;
    __syncthreads();
    int stride = gridDim.x * blockDim.x;
    for (int e = blockIdx.x * blockDim.x + threadIdx.x; e < ne; e += stride)
        atomicAdd(&lcnt[dst[e] >> BSHIFT], 1);
    __syncthreads();
    for (int t = threadIdx.x; t < NBMAX; t += blockDim.x)
        if (lcnt[t]) atomicAdd(&bcnt[t], lcnt[t]);
}

// scan 2048 entries with 1024 threads (2 per thread)
__global__ void k_scan(const int* __restrict__ bcnt, int* __restrict__ boff,
                       int* __restrict__ bcur) {
    __shared__ int s[1024];
    int t = threadIdx.x;
    int v0 = bcnt[2 * t], v1 = bcnt[2 * t + 1];
    int pair = v0 + v1;
    s[t] = pair;
    __syncthreads();
    for (int off = 1; off < 1024; off <<= 1) {
        int tv = (t >= off) ? s[t - off] : 0;
        __syncthreads();
        s[t] += tv;
        __syncthreads();
    }
    int ex = s[t] - pair;
    boff[2 * t] = ex;      bcur[2 * t] = ex;
    boff[2 * t + 1] = ex + v0;  bcur[2 * t + 1] = ex + v0;
}

__global__ void k_partition(const int* __restrict__ src, const int* __restrict__ dst,
                            int* __restrict__ bcur, unsigned int* __restrict__ bucketed,
                            int ne) {
    __shared__ unsigned int ebd[CHUNK];   // (bucket<<16)|dst_local
    __shared__ int lcnt[NBMAX];
    __shared__ int lbase[NBMAX];
    __shared__ int lcur[NBMAX];
    int t = threadIdx.x;
    long base = (long)blockIdx.x * CHUNK;
    for (int b = t; b < NBMAX; b += PB) lcnt[b] = 0;
    __syncthreads();
#pragma unroll
    for (int k = 0; k < EPT; k++) {
        int idx = t + k * PB;
        long e = base + idx;
        unsigned int v = 0xFFFF0000u;
        if (e < ne) {
            int d = dst[e];
            int b = d >> BSHIFT;
            v = ((unsigned int)b << 16) | (unsigned int)(d & (BW - 1));
            atomicAdd(&lcnt[b], 1);
        }
        ebd[idx] = v;
    }
    __syncthreads();
    for (int b = t; b < NBMAX; b += PB) {
        int c = lcnt[b];
        if (c > 0) lbase[b] = atomicAdd(&bcur[b], c);
        lcur[b] = 0;
    }
    __syncthreads();
#pragma unroll
    for (int k = 0; k < EPT; k++) {
        int idx = t + k * PB;
        unsigned int v = ebd[idx];
        unsigned int b = v >> 16;
        if (b == 0xFFFFu) continue;
        int r = atomicAdd(&lcur[b], 1);
        int s = src[base + idx];
        bucketed[lbase[b] + r] = ((unsigned int)s << BSHIFT) | (v & (BW - 1));
    }
}

__global__ void k_bucket_dinv(const unsigned int* __restrict__ bucketed,
                              const int* __restrict__ boff, const int* __restrict__ bcnt,
                              float* __restrict__ dinv, int n) {
    __shared__ int deg[BW];
    int b = blockIdx.x, t = threadIdx.x;
    if (t < BW) deg[t] = 0;
    __syncthreads();
    int s0 = boff[b], c = bcnt[b];
    for (int j = t; j < c; j += blockDim.x) atomicAdd(&deg[bucketed[s0 + j] & (BW - 1)], 1);
    __syncthreads();
    if (t < BW) {
        int node = (b << BSHIFT) + t;
        if (node < n) dinv[node] = rsqrtf((float)deg[t] + 1.0f);
    }
}

// hs1h = fp16((x @ W1) * dinv[i]) — 16 halves (32B) per node
__global__ void k_dense1(const float* __restrict__ x, const float* __restrict__ W1,
                         const float* __restrict__ dinv, __half2* __restrict__ hs1h, int n) {
    __shared__ float sW[NFEAT_IN * NHID];
    for (int t = threadIdx.x; t < NFEAT_IN * NHID; t += blockDim.x) sW[t] = W1[t];
    __syncthreads();
    int i = blockIdx.x * blockDim.x + threadIdx.x;
    if (i >= n) return;
    float xi[NFEAT_IN];
#pragma unroll
    for (int k = 0; k < NFEAT_IN; k++) xi[k] = x[(size_t)i * NFEAT_IN + k];
    float di = dinv[i];
    float r[NHID];
#pragma unroll
    for (int j = 0; j < NHID; j++) {
        float acc = 0.f;
#pragma unroll
        for (int k = 0; k < NFEAT_IN; k++) acc += xi[k] * sW[k * NHID + j];
        r[j] = acc * di;
    }
    __half2* hp = hs1h + (size_t)i * 8;
#pragma unroll
    for (int q = 0; q < 8; q++) hp[q] = __floats2half2_rn(r[2 * q], r[2 * q + 1]);
}

__device__ __forceinline__ void acc16(float* a, u32x4 u0, u32x4 u1) {
    unsigned int us[8] = {u0[0], u0[1], u0[2], u0[3], u1[0], u1[1], u1[2], u1[3]};
#pragma unroll
    for (int q = 0; q < 8; q++) {
        float2 f = __half22float2(*(const __half2*)&us[q]);
        atomicAdd(a + 2 * q, f.x);
        atomicAdd(a + 2 * q + 1, f.y);
    }
}

// bucket-centric aggregate layer1 + relu + dense2
// The DEPTH-8 gather pipeline MUST materialize (8 idx + 16 u32x4 payloads
// ~ 110 VGPR). Round-5/round-prev failure mode: machine scheduler sinks the
// payload loads into the acc loop (VGPR=40, 1 outstanding gather/wave,
// latency-bound at 0.8% VALU / 3.6% HBM). Fix: sched_barrier(0) fences pin
// {idx loads} -> {payload loads} -> {acc} ordering, plus keep-alive asm so
// no pass can re-serialize the batch. Success criterion: VGPR_Count >= ~100.
__global__ __launch_bounds__(256, 2) void
k_agg1(const unsigned int* __restrict__ bucketed, const int* __restrict__ boff,
       const int* __restrict__ bcnt, const __half2* __restrict__ hs1h,
       const float* __restrict__ b1, const float* __restrict__ W2,
       const float* __restrict__ dinv, __half2* __restrict__ hs2h, int n) {
    __shared__ float acc[BW * 17];
    __shared__ float sW[NHID * NOUT];
    __shared__ float sb[NHID];
    int b = blockIdx.x, t = threadIdx.x;
    for (int k = t; k < BW * 17; k += 256) acc[k] = 0.f;
    if (t < NHID * NOUT) sW[t] = W2[t];
    if (t < NHID) sb[t] = b1[t];
    __syncthreads();
    int s0 = boff[b], c = bcnt[b];
    const char* hbase = (const char*)hs1h;
    int nIter = (c - t + 255) >> 8;    // j = t + k*256 < c
    int kFull = (nIter / DEPTH) * DEPTH;
    int k0 = 0;
    for (; k0 < kFull; k0 += DEPTH) {
        unsigned int pk[DEPTH];
        u32x4 f0[DEPTH], f1[DEPTH];
#pragma unroll
        for (int q = 0; q < DEPTH; q++)
            pk[q] = __builtin_nontemporal_load(bucketed + s0 + t + (k0 + q) * 256);
        __builtin_amdgcn_sched_barrier(0);   // idx batch stays above
#pragma unroll
        for (int q = 0; q < DEPTH; q++) {
            const u32x4* a = (const u32x4*)(hbase + (size_t)(pk[q] >> BSHIFT) * 32);
            f0[q] = a[0];
            f1[q] = a[1];
        }
        __builtin_amdgcn_sched_barrier(0);   // payload batch stays above
        // keep-alive: force all 16 payloads live in VGPRs here (2 asms of 8
        // operands each to stay under inline-asm operand limits)
        asm volatile("" : "+v"(f0[0]), "+v"(f0[1]), "+v"(f0[2]), "+v"(f0[3]),
                          "+v"(f0[4]), "+v"(f0[5]), "+v"(f0[6]), "+v"(f0[7]));
        asm volatile("" : "+v"(f1[0]), "+v"(f1[1]), "+v"(f1[2]), "+v"(f1[3]),
                          "+v"(f1[4]), "+v"(f1[5]), "+v"(f1[6]), "+v"(f1[7]));
#pragma unroll
        for (int q = 0; q < DEPTH; q++)
            acc16(acc + (pk[q] & (BW - 1)) * 17, f0[q], f1[q]);
    }
    for (; k0 < nIter; k0++) {
        unsigned int p = __builtin_nontemporal_load(bucketed + s0 + t + k0 * 256);
        const u32x4* a = (const u32x4*)(hbase + (size_t)(p >> BSHIFT) * 32);
        u32x4 u0 = a[0], u1 = a[1];
        acc16(acc + (p & (BW - 1)) * 17, u0, u1);
    }
    __syncthreads();
    if (t >= BW) return;
    int node = (b << BSHIFT) + t;
    if (node >= n) return;
    float di = dinv[node];
    float z[NHID];
    {
        const u32x4* sp = (const u32x4*)(hbase + (size_t)node * 32);
        u32x4 s0v = sp[0], s1v = sp[1];
        unsigned int us[8] = {s0v[0], s0v[1], s0v[2], s0v[3], s1v[0], s1v[1], s1v[2], s1v[3]};
        float* a = acc + t * 17;
#pragma unroll
        for (int q = 0; q < 8; q++) {
            float2 f = __half22float2(*(const __half2*)&us[q]);
            z[2 * q]     = fmaxf((a[2 * q] + f.x) * di + sb[2 * q], 0.0f);
            z[2 * q + 1] = fmaxf((a[2 * q + 1] + f.y) * di + sb[2 * q + 1], 0.0f);
        }
    }
    float h[8];
#pragma unroll
    for (int kk = 0; kk < NOUT; kk++) {
        float s = 0.f;
#pragma unroll
        for (int jj = 0; jj < NHID; jj++) s += z[jj] * sW[jj * NOUT + kk];
        h[kk] = s * di;
    }
    h[6] = 0.f; h[7] = 0.f;
    __half2* op = hs2h + (size_t)node * 4;
#pragma unroll
    for (int q = 0; q < 4; q++) op[q] = __floats2half2_rn(h[2 * q], h[2 * q + 1]);
}

// bucket-centric aggregate layer2 + bias + log_softmax; DEPTH-8 pipeline
// with the same pinned-load-batch structure as k_agg1.
__global__ __launch_bounds__(256, 4) void
k_agg2(const unsigned int* __restrict__ bucketed, const int* __restrict__ boff,
       const int* __restrict__ bcnt, const __half2* __restrict__ hs2h,
       const float* __restrict__ b2, const float* __restrict__ dinv,
       float* __restrict__ out, int n) {
    __shared__ float acc[BW * 7];
    __shared__ float sb[NOUT];
    int b = blockIdx.x, t = threadIdx.x;
    for (int k = t; k < BW * 7; k += 256) acc[k] = 0.f;
    if (t < NOUT) sb[t] = b2[t];
    __syncthreads();
    int s0 = boff[b], c = bcnt[b];
    const char* hbase = (const char*)hs2h;
    int nIter = (c - t + 255) >> 8;
    int kFull = (nIter / DEPTH) * DEPTH;
    int k0 = 0;
    for (; k0 < kFull; k0 += DEPTH) {
        unsigned int pk[DEPTH];
        u32x4 f[DEPTH];
#pragma unroll
        for (int q = 0; q < DEPTH; q++)
            pk[q] = __builtin_nontemporal_load(bucketed + s0 + t + (k0 + q) * 256);
        __builtin_amdgcn_sched_barrier(0);   // idx batch stays above
#pragma unroll
        for (int q = 0; q < DEPTH; q++)
            f[q] = *(const u32x4*)(hbase + (size_t)(pk[q] >> BSHIFT) * 16);
        __builtin_amdgcn_sched_barrier(0);   // payload batch stays above
        asm volatile("" : "+v"(f[0]), "+v"(f[1]), "+v"(f[2]), "+v"(f[3]),
                          "+v"(f[4]), "+v"(f[5]), "+v"(f[6]), "+v"(f[7]));
#pragma unroll
        for (int q = 0; q < DEPTH; q++) {
            float* a = acc + (pk[q] & (BW - 1)) * 7;
            unsigned int us[3] = {f[q][0], f[q][1], f[q][2]};
#pragma unroll
            for (int w = 0; w < 3; w++) {
                float2 fv = __half22float2(*(const __half2*)&us[w]);
                atomicAdd(a + 2 * w, fv.x);
                atomicAdd(a + 2 * w + 1, fv.y);
            }
        }
    }
    for (; k0 < nIter; k0++) {
        unsigned int p = __builtin_nontemporal_load(bucketed + s0 + t + k0 * 256);
        u32x4 u = *(const u32x4*)(hbase + (size_t)(p >> BSHIFT) * 16);
        float* a = acc + (p & (BW - 1)) * 7;
        unsigned int us[3] = {u[0], u[1], u[2]};
#pragma unroll
        for (int w = 0; w < 3; w++) {
            float2 fv = __half22float2(*(const __half2*)&us[w]);
            atomicAdd(a + 2 * w, fv.x);
            atomicAdd(a + 2 * w + 1, fv.y);
        }
    }
    __syncthreads();
    if (t >= BW) return;
    int node = (b << BSHIFT) + t;
    if (node >= n) return;
    float di = dinv[node];
    u32x4 sv = *(const u32x4*)(hbase + (size_t)node * 16);
    unsigned int us[3] = {sv[0], sv[1], sv[2]};
    float v[NOUT];
    float* a = acc + t * 7;
#pragma unroll
    for (int q = 0; q < 3; q++) {
        float2 f = __half22float2(*(const __half2*)&us[q]);
        v[2 * q]     = (a[2 * q] + f.x) * di + sb[2 * q];
        v[2 * q + 1] = (a[2 * q + 1] + f.y) * di + sb[2 * q + 1];
    }
    float m = -1e30f;
#pragma unroll
    for (int k = 0; k < NOUT; k++) m = fmaxf(m, v[k]);
    float se = 0.f;
#pragma unroll
    for (int k = 0; k < NOUT; k++) se += expf(v[k] - m);
    float l = logf(se);
#pragma unroll
    for (int k = 0; k < NOUT; k++) out[(size_t)node * NOUT + k] = v[k] - m - l;
}

extern "C" void kernel_launch(void* const* d_in, const int* in_sizes, int n_in,
                              void* d_out, int out_size, void* d_ws, size_t ws_size,
                              hipStream_t stream) {
    const float* x  = (const float*)d_in[0];
    const int*   ei = (const int*)d_in[1];
    const float* W1 = (const float*)d_in[2];
    const float* b1 = (const float*)d_in[3];
    const float* W2 = (const float*)d_in[4];
    const float* b2 = (const float*)d_in[5];
    float* out = (float*)d_out;

    int n  = in_sizes[0] / NFEAT_IN;   // 200000
    int ne = in_sizes[1] / 2;          // 6400000
    const int* src = ei;
    const int* dst = ei + ne;

    char* base = (char*)d_ws;
    size_t off = 0;
    auto alloc = [&](size_t bytes) {
        void* p = base + off;
        off += (bytes + 63) & ~(size_t)63;
        return p;
    };
    int* bcnt = (int*)alloc(NBMAX * 4);
    int* boff = (int*)alloc(NBMAX * 4);
    int* bcur = (int*)alloc(NBMAX * 4);
    unsigned int* bucketed = (unsigned int*)alloc((size_t)ne * 4);
    float*   dinv = (float*)alloc((size_t)n * 4);
    __half2* hs1h = (__half2*)alloc((size_t)n * 32);
    __half2* hs2h = (__half2*)alloc((size_t)n * 16);

    int nb = (n + BW - 1) >> BSHIFT;          // 1563
    int gp = (ne + CHUNK - 1) / CHUNK;        // 782
    int gn = (n + 255) / 256;

    k_zero<<<(NBMAX + 255) / 256, 256, 0, stream>>>(bcnt, NBMAX);
    k_hist<<<256, 256, 0, stream>>>(dst, bcnt, ne);
    k_scan<<<1, 1024, 0, stream>>>(bcnt, boff, bcur);
    k_partition<<<gp, PB, 0, stream>>>(src, dst, bcur, bucketed, ne);
    k_bucket_dinv<<<nb, 256, 0, stream>>>(bucketed, boff, bcnt, dinv, n);
    k_dense1<<<gn, 256, 0, stream>>>(x, W1, dinv, hs1h, n);
    k_agg1<<<nb, 256, 0, stream>>>(bucketed, boff, bcnt, hs1h, b1, W2, dinv, hs2h, n);
    k_agg2<<<nb, 256, 0, stream>>>(bucketed, boff, bcnt, hs2h, b2, dinv, out, n);
}

// Round 3
// 462.029 us; speedup vs baseline: 2.3318x; 2.3318x over previous
//
#include <hip/hip_runtime.h>
#include <hip/hip_fp16.h>

#define NFEAT_IN 21
#define NHID 16
#define NOUT 6
#define BSHIFT 7
#define BW (1 << BSHIFT)     // 128 nodes per bucket
#define NBMAX 2048           // supports n <= 262144
#define EPT 32
#define PB 256
#define CHUNK (PB * EPT)     // 8192 edges per partition block

typedef unsigned int u32x4 __attribute__((ext_vector_type(4)));

__global__ void k_zero(int* __restrict__ p, int n) {
    int i = blockIdx.x * blockDim.x + threadIdx.x;
    if (i < n) p[i] = 0;
}

__global__ void k_hist(const int* __restrict__ dst, int* __restrict__ bcnt, int ne) {
    __shared__ int lcnt[NBMAX];
    for (int t = threadIdx.x; t < NBMAX; t += blockDim.x) lcnt[t] = 0;
    __syncthreads();
    int stride = gridDim.x * blockDim.x;
    for (int e = blockIdx.x * blockDim.x + threadIdx.x; e < ne; e += stride)
        atomicAdd(&lcnt[dst[e] >> BSHIFT], 1);
    __syncthreads();
    for (int t = threadIdx.x; t < NBMAX; t += blockDim.x)
        if (lcnt[t]) atomicAdd(&bcnt[t], lcnt[t]);
}

// scan 2048 entries with 1024 threads (2 per thread)
__global__ void k_scan(const int* __restrict__ bcnt, int* __restrict__ boff,
                       int* __restrict__ bcur) {
    __shared__ int s[1024];
    int t = threadIdx.x;
    int v0 = bcnt[2 * t], v1 = bcnt[2 * t + 1];
    int pair = v0 + v1;
    s[t] = pair;
    __syncthreads();
    for (int off = 1; off < 1024; off <<= 1) {
        int tv = (t >= off) ? s[t - off] : 0;
        __syncthreads();
        s[t] += tv;
        __syncthreads();
    }
    int ex = s[t] - pair;
    boff[2 * t] = ex;      bcur[2 * t] = ex;
    boff[2 * t + 1] = ex + v0;  bcur[2 * t + 1] = ex + v0;
}

__global__ void k_partition(const int* __restrict__ src, const int* __restrict__ dst,
                            int* __restrict__ bcur, unsigned int* __restrict__ bucketed,
                            int ne) {
    __shared__ unsigned int ebd[CHUNK];   // (bucket<<16)|dst_local
    __shared__ int lcnt[NBMAX];
    __shared__ int lbase[NBMAX];
    __shared__ int lcur[NBMAX];
    int t = threadIdx.x;
    long base = (long)blockIdx.x * CHUNK;
    for (int b = t; b < NBMAX; b += PB) lcnt[b] = 0;
    __syncthreads();
#pragma unroll
    for (int k = 0; k < EPT; k++) {
        int idx = t + k * PB;
        long e = base + idx;
        unsigned int v = 0xFFFF0000u;
        if (e < ne) {
            int d = dst[e];
            int b = d >> BSHIFT;
            v = ((unsigned int)b << 16) | (unsigned int)(d & (BW - 1));
            atomicAdd(&lcnt[b], 1);
        }
        ebd[idx] = v;
    }
    __syncthreads();
    for (int b = t; b < NBMAX; b += PB) {
        int c = lcnt[b];
        if (c > 0) lbase[b] = atomicAdd(&bcur[b], c);
        lcur[b] = 0;
    }
    __syncthreads();
#pragma unroll
    for (int k = 0; k < EPT; k++) {
        int idx = t + k * PB;
        unsigned int v = ebd[idx];
        unsigned int b = v >> 16;
        if (b == 0xFFFFu) continue;
        int r = atomicAdd(&lcur[b], 1);
        int s = src[base + idx];
        bucketed[lbase[b] + r] = ((unsigned int)s << BSHIFT) | (v & (BW - 1));
    }
}

// Counting-sort each bucket by dst_local -> exact dst-sorted CSR.
// Produces csr_src (src id per edge, grouped by dst node) and node_off
// (global exclusive offsets; node_off[i+1]-node_off[i] = in-degree of i).
// Also emits dinv (replaces k_bucket_dinv).
__global__ __launch_bounds__(256) void
k_sort(const unsigned int* __restrict__ bucketed, const int* __restrict__ boff,
       const int* __restrict__ bcnt, int* __restrict__ csr_src,
       int* __restrict__ node_off, float* __restrict__ dinv,
       int n, int ne, int nb) {
    __shared__ int bin[BW];
    __shared__ int sc[BW];
    __shared__ int bcur[BW];
    int b = blockIdx.x, t = threadIdx.x;
    if (t < BW) bin[t] = 0;
    __syncthreads();
    int s0 = boff[b], c = bcnt[b];
    for (int j = t; j < c; j += 256) atomicAdd(&bin[bucketed[s0 + j] & (BW - 1)], 1);
    __syncthreads();
    if (t < BW) sc[t] = bin[t];
    __syncthreads();
    for (int off = 1; off < BW; off <<= 1) {
        int v = 0;
        if (t < BW && t >= off) v = sc[t - off];
        __syncthreads();
        if (t < BW) sc[t] += v;
        __syncthreads();
    }
    if (t < BW) {
        int ex = sc[t] - bin[t];            // exclusive prefix
        bcur[t] = s0 + ex;
        node_off[(b << BSHIFT) + t] = s0 + ex;
        int node = (b << BSHIFT) + t;
        if (node < n) dinv[node] = rsqrtf((float)bin[t] + 1.0f);
    }
    if (b == 0 && t == 0) node_off[nb << BSHIFT] = ne;  // sentinel
    __syncthreads();
    for (int j = t; j < c; j += 256) {
        unsigned int e = bucketed[s0 + j];
        int pos = atomicAdd(&bcur[e & (BW - 1)], 1);
        csr_src[pos] = (int)(e >> BSHIFT);
    }
}

// hs1h = fp16((x @ W1) * dinv[i]) — 16 halves (32B) per node
__global__ void k_dense1(const float* __restrict__ x, const float* __restrict__ W1,
                         const float* __restrict__ dinv, __half2* __restrict__ hs1h, int n) {
    __shared__ float sW[NFEAT_IN * NHID];
    for (int t = threadIdx.x; t < NFEAT_IN * NHID; t += blockDim.x) sW[t] = W1[t];
    __syncthreads();
    int i = blockIdx.x * blockDim.x + threadIdx.x;
    if (i >= n) return;
    float xi[NFEAT_IN];
#pragma unroll
    for (int k = 0; k < NFEAT_IN; k++) xi[k] = x[(size_t)i * NFEAT_IN + k];
    float di = dinv[i];
    float r[NHID];
#pragma unroll
    for (int j = 0; j < NHID; j++) {
        float acc = 0.f;
#pragma unroll
        for (int k = 0; k < NFEAT_IN; k++) acc += xi[k] * sW[k * NHID + j];
        r[j] = acc * di;
    }
    __half2* hp = hs1h + (size_t)i * 8;
#pragma unroll
    for (int q = 0; q < 8; q++) hp[q] = __floats2half2_rn(r[2 * q], r[2 * q + 1]);
}

__device__ __forceinline__ void addh16(float* acc, u32x4 u0, u32x4 u1) {
    unsigned int us[8] = {u0[0], u0[1], u0[2], u0[3], u1[0], u1[1], u1[2], u1[3]};
#pragma unroll
    for (int q = 0; q < 8; q++) {
        float2 f = __half22float2(*(const __half2*)&us[q]);
        acc[2 * q] += f.x;
        acc[2 * q + 1] += f.y;
    }
}

// CSR aggregate layer1 + relu + dense2. One thread per dst node; register
// accumulation — ZERO LDS atomics (round-1 finding: k_agg1 was LDS-atomic
// throughput bound at ~3.6cy/atomic-lane-op, 16 atomics/edge = 604us).
__global__ __launch_bounds__(256) void
k_agg1(const int* __restrict__ csr_src, const int* __restrict__ node_off,
       const __half2* __restrict__ hs1h, const float* __restrict__ b1,
       const float* __restrict__ W2, const float* __restrict__ dinv,
       __half2* __restrict__ hs2h, int n) {
    __shared__ float sW[NHID * NOUT];
    __shared__ float sb[NHID];
    int t = threadIdx.x;
    if (t < NHID * NOUT) sW[t] = W2[t];
    if (t < NHID) sb[t] = b1[t];
    __syncthreads();
    int i = blockIdx.x * blockDim.x + t;
    if (i >= n) return;
    int beg = node_off[i], end = node_off[i + 1];
    const u32x4* hb = (const u32x4*)hs1h;
    float acc[NHID];
    {   // self contribution (self-loop: A+I)
        u32x4 u0 = hb[(size_t)i * 2], u1 = hb[(size_t)i * 2 + 1];
        unsigned int us[8] = {u0[0], u0[1], u0[2], u0[3], u1[0], u1[1], u1[2], u1[3]};
#pragma unroll
        for (int q = 0; q < 8; q++) {
            float2 f = __half22float2(*(const __half2*)&us[q]);
            acc[2 * q] = f.x;
            acc[2 * q + 1] = f.y;
        }
    }
    int j = beg;
    for (; j + 4 <= end; j += 4) {
        int s0_ = csr_src[j], s1_ = csr_src[j + 1];
        int s2_ = csr_src[j + 2], s3_ = csr_src[j + 3];
        u32x4 a0 = hb[(size_t)s0_ * 2], a1 = hb[(size_t)s0_ * 2 + 1];
        u32x4 b0 = hb[(size_t)s1_ * 2], b1v = hb[(size_t)s1_ * 2 + 1];
        u32x4 c0 = hb[(size_t)s2_ * 2], c1 = hb[(size_t)s2_ * 2 + 1];
        u32x4 d0 = hb[(size_t)s3_ * 2], d1 = hb[(size_t)s3_ * 2 + 1];
        addh16(acc, a0, a1);
        addh16(acc, b0, b1v);
        addh16(acc, c0, c1);
        addh16(acc, d0, d1);
    }
    for (; j < end; j++) {
        int s_ = csr_src[j];
        addh16(acc, hb[(size_t)s_ * 2], hb[(size_t)s_ * 2 + 1]);
    }
    float di = dinv[i];
    float z[NHID];
#pragma unroll
    for (int k = 0; k < NHID; k++) z[k] = fmaxf(acc[k] * di + sb[k], 0.0f);
    float h[8];
#pragma unroll
    for (int kk = 0; kk < NOUT; kk++) {
        float s = 0.f;
#pragma unroll
        for (int jj = 0; jj < NHID; jj++) s += z[jj] * sW[jj * NOUT + kk];
        h[kk] = s * di;
    }
    h[6] = 0.f; h[7] = 0.f;
    __half2* op = hs2h + (size_t)i * 4;
#pragma unroll
    for (int q = 0; q < 4; q++) op[q] = __floats2half2_rn(h[2 * q], h[2 * q + 1]);
}

// CSR aggregate layer2 + bias + log_softmax. One thread per dst node.
__global__ __launch_bounds__(256) void
k_agg2(const int* __restrict__ csr_src, const int* __restrict__ node_off,
       const __half2* __restrict__ hs2h, const float* __restrict__ b2,
       const float* __restrict__ dinv, float* __restrict__ out, int n) {
    __shared__ float sb[NOUT];
    int t = threadIdx.x;
    if (t < NOUT) sb[t] = b2[t];
    __syncthreads();
    int i = blockIdx.x * blockDim.x + t;
    if (i >= n) return;
    int beg = node_off[i], end = node_off[i + 1];
    const u32x4* hb = (const u32x4*)hs2h;
    float acc[NOUT];
    {   // self
        u32x4 u = hb[(size_t)i];
        unsigned int us[3] = {u[0], u[1], u[2]};
#pragma unroll
        for (int q = 0; q < 3; q++) {
            float2 f = __half22float2(*(const __half2*)&us[q]);
            acc[2 * q] = f.x;
            acc[2 * q + 1] = f.y;
        }
    }
    int j = beg;
    for (; j + 8 <= end; j += 8) {
        int sid[8];
#pragma unroll
        for (int q = 0; q < 8; q++) sid[q] = csr_src[j + q];
        u32x4 u[8];
#pragma unroll
        for (int q = 0; q < 8; q++) u[q] = hb[(size_t)sid[q]];
#pragma unroll
        for (int q = 0; q < 8; q++) {
            unsigned int us[3] = {u[q][0], u[q][1], u[q][2]};
#pragma unroll
            for (int w = 0; w < 3; w++) {
                float2 f = __half22float2(*(const __half2*)&us[w]);
                acc[2 * w] += f.x;
                acc[2 * w + 1] += f.y;
            }
        }
    }
    for (; j < end; j++) {
        u32x4 u = hb[(size_t)csr_src[j]];
        unsigned int us[3] = {u[0], u[1], u[2]};
#pragma unroll
        for (int w = 0; w < 3; w++) {
            float2 f = __half22float2(*(const __half2*)&us[w]);
            acc[2 * w] += f.x;
            acc[2 * w + 1] += f.y;
        }
    }
    float di = dinv[i];
    float v[NOUT];
#pragma unroll
    for (int k = 0; k < NOUT; k++) v[k] = acc[k] * di + sb[k];
    float m = -1e30f;
#pragma unroll
    for (int k = 0; k < NOUT; k++) m = fmaxf(m, v[k]);
    float se = 0.f;
#pragma unroll
    for (int k = 0; k < NOUT; k++) se += expf(v[k] - m);
    float l = logf(se);
#pragma unroll
    for (int k = 0; k < NOUT; k++) out[(size_t)i * NOUT + k] = v[k] - m - l;
}

extern "C" void kernel_launch(void* const* d_in, const int* in_sizes, int n_in,
                              void* d_out, int out_size, void* d_ws, size_t ws_size,
                              hipStream_t stream) {
    const float* x  = (const float*)d_in[0];
    const int*   ei = (const int*)d_in[1];
    const float* W1 = (const float*)d_in[2];
    const float* b1 = (const float*)d_in[3];
    const float* W2 = (const float*)d_in[4];
    const float* b2 = (const float*)d_in[5];
    float* out = (float*)d_out;

    int n  = in_sizes[0] / NFEAT_IN;   // 200000
    int ne = in_sizes[1] / 2;          // 6400000
    const int* src = ei;
    const int* dst = ei + ne;

    char* base = (char*)d_ws;
    size_t off = 0;
    auto alloc = [&](size_t bytes) {
        void* p = base + off;
        off += (bytes + 63) & ~(size_t)63;
        return p;
    };
    int* bcnt = (int*)alloc(NBMAX * 4);
    int* boff = (int*)alloc(NBMAX * 4);
    int* bcur = (int*)alloc(NBMAX * 4);
    unsigned int* bucketed = (unsigned int*)alloc((size_t)ne * 4);
    int* csr_src  = (int*)alloc((size_t)ne * 4);
    int* node_off = (int*)alloc(((size_t)NBMAX + 1) * BW * 4);
    float* dinv = (float*)alloc((size_t)n * 4);
    // hs1h/hs2h overlay bucketed (dead after k_sort; hs* first written after)
    // to keep peak workspace low. Fallback to fresh allocs if shapes too small.
    __half2* hs1h;
    __half2* hs2h;
    if ((size_t)ne * 4 >= (size_t)n * 48) {
        hs1h = (__half2*)bucketed;
        hs2h = (__half2*)((char*)bucketed + (size_t)n * 32);
    } else {
        hs1h = (__half2*)alloc((size_t)n * 32);
        hs2h = (__half2*)alloc((size_t)n * 16);
    }

    int nb = (n + BW - 1) >> BSHIFT;          // 1563
    int gp = (ne + CHUNK - 1) / CHUNK;        // 782
    int gn = (n + 255) / 256;

    k_zero<<<(NBMAX + 255) / 256, 256, 0, stream>>>(bcnt, NBMAX);
    k_hist<<<256, 256, 0, stream>>>(dst, bcnt, ne);
    k_scan<<<1, 1024, 0, stream>>>(bcnt, boff, bcur);
    k_partition<<<gp, PB, 0, stream>>>(src, dst, bcur, bucketed, ne);
    k_sort<<<nb, 256, 0, stream>>>(bucketed, boff, bcnt, csr_src, node_off, dinv, n, ne, nb);
    k_dense1<<<gn, 256, 0, stream>>>(x, W1, dinv, hs1h, n);
    k_agg1<<<gn, 256, 0, stream>>>(csr_src, node_off, hs1h, b1, W2, dinv, hs2h, n);
    k_agg2<<<gn, 256, 0, stream>>>(csr_src, node_off, hs2h, b2, dinv, out, n);
}